// Round 14
// baseline (300.846 us; speedup 1.0000x reference)
//
#include <hip/hip_runtime.h>

#define NNODES 40960
#define NEDGES 81920
#define NG     1024
#define NCOMBO 512

// ---------- fused node encoder: x[n,:], then out_init[n,:] = bias + x@root ---
__global__ __launch_bounds__(256) void k_node(
    const int* __restrict__ nf, const float* __restrict__ emb,
    const float* __restrict__ root, const float* __restrict__ bias,
    float* __restrict__ x, float* __restrict__ out) {
    __shared__ float sx[4][64];
    const int t = threadIdx.x;
    const int ln = t >> 6;                 // local node 0..3
    const int d  = t & 63;
    const int n  = blockIdx.x * 4 + ln;
    const int* nfr = nf + n * 9;
    float acc = 0.f;
#pragma unroll
    for (int c = 0; c < 9; ++c) {
        int idx = nfr[c];
        acc += emb[((c << 7) + idx) * 64 + d];
    }
    x[n * 64 + d] = acc;
    sx[ln][d] = acc;
    __syncthreads();
    if (d < 32) {
        float o = bias[d];
#pragma unroll
        for (int k = 0; k < 64; ++k) o += sx[ln][k] * root[k * 32 + d];
        out[n * 32 + d] = o;
    }
}

// ---------- h1[c,:] = relu(etab[c] @ gW1), etab computed in-LDS ----------
__global__ __launch_bounds__(256) void k_h1(
    const float* __restrict__ bemb, const float* __restrict__ gW1,
    float* __restrict__ h1) {
    __shared__ float se[16];
    const int b = blockIdx.x, t = threadIdx.x;
    const int c = b >> 2;
    const int n = ((b & 3) << 8) + t;
    if (t < 16) {
        int f0 = c >> 6, f1 = (c >> 3) & 7, f2 = c & 7;
        se[t] = bemb[f0 * 16 + t] + bemb[(8 + f1) * 16 + t] +
                bemb[(16 + f2) * 16 + t];
    }
    __syncthreads();
    float acc = 0.f;
#pragma unroll
    for (int k = 0; k < 16; ++k) acc += se[k] * gW1[k * 1024 + n];
    h1[c * 1024 + n] = fmaxf(acc, 0.f);
}

// ---------- tiled GEMM, 64x64 block tile, 4x4 micro tile, split-K over z ------
template <int BM, int BN, int BK, int TM, int TN>
__global__ __launch_bounds__(256)
void k_gemm_tiled(const float* __restrict__ A, const float* __restrict__ B,
                  const float* __restrict__ bias, float* __restrict__ C,
                  float* __restrict__ Cp, int M, int N, int K, int KS, int relu) {
    constexpr int TX = BN / TN;                 // 16
    constexpr int TY = BM / TM;                 // 16
    static_assert(TX * TY == 256, "block must be 256 threads");
    __shared__ float As[BK][BM + 4];            // transposed A tile
    __shared__ float Bs[BK][BN + 4];
    const int tx = threadIdx.x % TX, ty = threadIdx.x / TX;
    const int row0 = blockIdx.y * BM, col0 = blockIdx.x * BN;
    const int z = blockIdx.z;
    const int k_begin = z * KS, k_end = k_begin + KS;

    const int am = threadIdx.x >> 2;            // 0..63
    const int ak = (threadIdx.x & 3) << 2;      // 0,4,8,12
    const int bk = threadIdx.x >> 4;            // 0..15
    const int bn = (threadIdx.x & 15) << 2;     // 0..60

    float acc[TM][TN] = {};
    for (int k0 = k_begin; k0 < k_end; k0 += BK) {
        float4 av = *reinterpret_cast<const float4*>(&A[(row0 + am) * K + k0 + ak]);
        float4 bv = *reinterpret_cast<const float4*>(&B[(k0 + bk) * N + col0 + bn]);
        As[ak + 0][am] = av.x;
        As[ak + 1][am] = av.y;
        As[ak + 2][am] = av.z;
        As[ak + 3][am] = av.w;
        *reinterpret_cast<float4*>(&Bs[bk][bn]) = bv;
        __syncthreads();
#pragma unroll
        for (int k = 0; k < BK; ++k) {
            float a[TM], b[TN];
            *reinterpret_cast<float4*>(a) =
                *reinterpret_cast<const float4*>(&As[k][ty * TM]);
            *reinterpret_cast<float4*>(b) =
                *reinterpret_cast<const float4*>(&Bs[k][tx * TN]);
#pragma unroll
            for (int i = 0; i < TM; ++i)
#pragma unroll
                for (int j = 0; j < TN; ++j) acc[i][j] += a[i] * b[j];
        }
        __syncthreads();
    }

    const int MN = M * N;
    if (gridDim.z == 1) {
#pragma unroll
        for (int i = 0; i < TM; ++i) {
            int r = row0 + ty * TM + i;
            float4 v;
            v.x = acc[i][0]; v.y = acc[i][1]; v.z = acc[i][2]; v.w = acc[i][3];
            int c = col0 + tx * TN;
            if (bias) { v.x += bias[c]; v.y += bias[c+1]; v.z += bias[c+2]; v.w += bias[c+3]; }
            if (relu) { v.x = fmaxf(v.x,0.f); v.y = fmaxf(v.y,0.f);
                        v.z = fmaxf(v.z,0.f); v.w = fmaxf(v.w,0.f); }
            *reinterpret_cast<float4*>(&C[r * N + c]) = v;
        }
    } else {
        float* dstp = Cp + z * MN;
#pragma unroll
        for (int i = 0; i < TM; ++i) {
            int r = row0 + ty * TM + i;
            float4 v;
            v.x = acc[i][0]; v.y = acc[i][1]; v.z = acc[i][2]; v.w = acc[i][3];
            *reinterpret_cast<float4*>(&dstp[r * N + col0 + tx * TN]) = v;
        }
    }
}

// ---------- split-K reduce: C = relu?(sum_z Cp[z] + bias) ----------
__global__ void k_reduceK(const float* __restrict__ Cp, const float* __restrict__ bias,
                          float* __restrict__ C, int MN, int N, int nz, int relu) {
    int i4 = (blockIdx.x * 256 + threadIdx.x) * 4;
    if (i4 >= MN) return;
    float4 acc = *reinterpret_cast<const float4*>(&Cp[i4]);
    for (int z = 1; z < nz; ++z) {
        float4 t = *reinterpret_cast<const float4*>(&Cp[z * MN + i4]);
        acc.x += t.x; acc.y += t.y; acc.z += t.z; acc.w += t.w;
    }
    if (bias) {
        int c = i4 % N;
        acc.x += bias[c]; acc.y += bias[c + 1]; acc.z += bias[c + 2]; acc.w += bias[c + 3];
    }
    if (relu) {
        acc.x = fmaxf(acc.x, 0.f); acc.y = fmaxf(acc.y, 0.f);
        acc.z = fmaxf(acc.z, 0.f); acc.w = fmaxf(acc.w, 0.f);
    }
    *reinterpret_cast<float4*>(&C[i4]) = acc;
}

// ---------- split-K reduce for wtab, writing TRANSPOSED: WT[c][o][k] ---------
// i4 covers 4 consecutive j = k*32 + o..o+3 (same k). Reads coalesced;
// 4 stride-256B stores per thread land in L2 (4 MB table).
__global__ void k_reduceT(const float* __restrict__ Cp, float* __restrict__ WT) {
    int i4 = (blockIdx.x * 256 + threadIdx.x) * 4;     // over 512*2048
    float4 a = *reinterpret_cast<const float4*>(&Cp[i4]);
    float4 b = *reinterpret_cast<const float4*>(&Cp[1048576 + i4]);
    a.x += b.x; a.y += b.y; a.z += b.z; a.w += b.w;
    int c = i4 >> 11, j = i4 & 2047;
    int k = j >> 5, o = j & 31;
    float* base = WT + c * 2048 + k;
    base[(o + 0) * 64] = a.x;
    base[(o + 1) * 64] = a.y;
    base[(o + 2) * 64] = a.z;
    base[(o + 3) * 64] = a.w;
}

// ---------- NNConv message + scatter, o-major W: 32 wide loads, short chains -
// Thread (e,o): 16 broadcast x-float4 + 16 CONTIGUOUS W-float4 loads feeding
// 64 FMAs (ascending k, single accumulator — bit-identical to round-0 order).
// 32 independent float4 loads pipeline within the default VGPR budget.
__global__ void k_msgT(const float* __restrict__ x, const float* __restrict__ wt,
                       const int* __restrict__ ef, const int* __restrict__ src,
                       const int* __restrict__ dst, float* __restrict__ out) {
    int gid = blockIdx.x * blockDim.x + threadIdx.x;   // NEDGES*32
    int e = gid >> 5, o = gid & 31;
    int s = src[e], d = dst[e];
    int c = (ef[e * 3] << 6) | (ef[e * 3 + 1] << 3) | ef[e * 3 + 2];
    const float4* xv = reinterpret_cast<const float4*>(x + s * 64);
    const float4* wv = reinterpret_cast<const float4*>(wt + c * 2048 + o * 64);
    float acc = 0.f;
#pragma unroll
    for (int k4 = 0; k4 < 16; ++k4) {
        float4 q = xv[k4];
        float4 w = wv[k4];
        acc += q.x * w.x;
        acc += q.y * w.y;
        acc += q.z * w.z;
        acc += q.w * w.w;
    }
    atomicAdd(&out[d * 32 + o], acc);
}

// ---------- fused readout tail: f1 -> f2 -> f3 -> f4 -> out, 4 graphs/block --
__global__ __launch_bounds__(256) void k_tail2(
    const float* __restrict__ f1,
    const float* __restrict__ mW2, const float* __restrict__ mb2,
    const float* __restrict__ mW3, const float* __restrict__ mb3,
    const float* __restrict__ mW4, const float* __restrict__ mb4,
    const float* __restrict__ mW5, const float* __restrict__ mb5,
    float* __restrict__ outv) {
    __shared__ float s1[4][256];
    __shared__ float s2[4][128];
    __shared__ float s3[4][32];
    __shared__ float s4[4][8];
    const int t  = threadIdx.x;
    const int g0 = blockIdx.x * 4;
#pragma unroll
    for (int i = 0; i < 4; ++i) {
        int idx = t + i * 256;
        s1[idx >> 8][idx & 255] = f1[g0 * 256 + idx];
    }
    __syncthreads();
#pragma unroll
    for (int i = 0; i < 2; ++i) {
        int idx = t + i * 256;
        int g = idx >> 7, cc = idx & 127;
        float acc = mb2[cc];
#pragma unroll 8
        for (int k = 0; k < 256; ++k) acc += s1[g][k] * mW2[k * 128 + cc];
        s2[g][cc] = fmaxf(acc, 0.f);
    }
    __syncthreads();
    const int w = t >> 6, lane = t & 63;
    if (lane < 32) {
        float acc = mb3[lane];
#pragma unroll 8
        for (int k = 0; k < 128; ++k) acc += s2[w][k] * mW3[k * 32 + lane];
        s3[w][lane] = fmaxf(acc, 0.f);
    }
    __syncthreads();
    if (lane < 8) {
        float acc = mb4[lane];
#pragma unroll
        for (int k = 0; k < 32; ++k) acc += s3[w][k] * mW4[k * 8 + lane];
        s4[w][lane] = fmaxf(acc, 0.f);
    }
    __syncthreads();
    if (lane == 0) {
        float acc = mb5[0];
#pragma unroll
        for (int k = 0; k < 8; ++k) acc += s4[w][k] * mW5[k];
        outv[g0 + w] = acc;
    }
}

extern "C" void kernel_launch(void* const* d_in, const int* in_sizes, int n_in,
                              void* d_out, int out_size, void* d_ws, size_t ws_size,
                              hipStream_t stream) {
    const int*   nf      = (const int*)d_in[0];
    const int*   ef      = (const int*)d_in[1];
    const int*   eidx    = (const int*)d_in[2];
    const float* atom_emb= (const float*)d_in[4];
    const float* bond_emb= (const float*)d_in[5];
    const float* gW1     = (const float*)d_in[6];
    const float* gW2     = (const float*)d_in[7];
    const float* gW3     = (const float*)d_in[8];
    const float* root    = (const float*)d_in[9];
    const float* cbias   = (const float*)d_in[10];
    const float* mW1     = (const float*)d_in[11];
    const float* mb1     = (const float*)d_in[12];
    const float* mW2     = (const float*)d_in[13];
    const float* mb2     = (const float*)d_in[14];
    const float* mW3     = (const float*)d_in[15];
    const float* mb3     = (const float*)d_in[16];
    const float* mW4     = (const float*)d_in[17];
    const float* mb4     = (const float*)d_in[18];
    const float* mW5     = (const float*)d_in[19];
    const float* mb5     = (const float*)d_in[20];

    const int* src = eidx;
    const int* dst = eidx + NEDGES;

    float* ws = (float*)d_ws;
    float* x    = ws;                        // 40960*64   = 2621440
    float* out  = x + 2621440;               // 40960*32   = 1310720
    float* h1   = out + 1310720;             // 512*1024   = 524288
    float* h2   = h1 + 524288;               // 512*256    = 131072
    float* wtab = h2 + 131072;               // 512*2048   = 1048576 (o-major WT)
    float* f1   = wtab + 1048576;            // 1024*256   = 262144
    float* part = f1 + 262144;               // 2097152 (8 MB split-K partials)

    // 1. fused atom encoder + root transform
    k_node<<<NNODES / 4, 256, 0, stream>>>(nf, atom_emb, root, cbias, x, out);
    // 2. h1 = relu(etab @ gW1), etab computed in-LDS per block
    k_h1<<<NCOMBO * 4, 256, 0, stream>>>(bond_emb, gW1, h1);
    // 3. h2 = relu(h1 @ gW2): 512x256, K=1024, split 16x64
    k_gemm_tiled<64, 64, 16, 4, 4><<<dim3(4, 8, 16), 256, 0, stream>>>(
        h1, gW2, nullptr, nullptr, part, NCOMBO, 256, 1024, 64, 0);
    k_reduceK<<<131072 / 1024, 256, 0, stream>>>(part, nullptr, h2, 131072, 256, 16, 1);
    // 4. wtab(T) = (h2 @ gW3)^T per combo: 512x2048, K=256, split 2x128,
    //    reduce writes o-major layout WT[c][o][k]
    k_gemm_tiled<64, 64, 16, 4, 4><<<dim3(32, 8, 2), 256, 0, stream>>>(
        h2, gW3, nullptr, nullptr, part, NCOMBO, 2048, 256, 128, 0);
    k_reduceT<<<1048576 / 1024, 256, 0, stream>>>(part, wtab);
    // 5. per-edge message + scatter: o-major W, 32 wide loads/thread
    k_msgT<<<NEDGES * 32 / 256, 256, 0, stream>>>(x, wtab, ef, src, dst, out);
    // 6. f1 = relu(dense @ mW1 + mb1): 1024x256, K=1280, split 8x160
    k_gemm_tiled<64, 64, 16, 4, 4><<<dim3(4, 16, 8), 256, 0, stream>>>(
        out, mW1, nullptr, nullptr, part, NG, 256, 1280, 160, 0);
    k_reduceK<<<262144 / 1024, 256, 0, stream>>>(part, mb1, f1, 262144, 256, 8, 1);
    // 7. fused tail: f2, f3, f4, final
    k_tail2<<<NG / 4, 256, 0, stream>>>(f1, mW2, mb2, mW3, mb3, mW4, mb4,
                                        mW5, mb5, (float*)d_out);
}

// Round 15
// 233.961 us; speedup vs baseline: 1.2859x; 1.2859x over previous
//
#include <hip/hip_runtime.h>

#define NNODES 40960
#define NEDGES 81920
#define NG     1024
#define NCOMBO 512

// ---------- fused node encoder: x[n,:], then out_init[n,:] = bias + x@root ---
__global__ __launch_bounds__(256) void k_node(
    const int* __restrict__ nf, const float* __restrict__ emb,
    const float* __restrict__ root, const float* __restrict__ bias,
    float* __restrict__ x, float* __restrict__ out) {
    __shared__ float sx[4][64];
    const int t = threadIdx.x;
    const int ln = t >> 6;                 // local node 0..3
    const int d  = t & 63;
    const int n  = blockIdx.x * 4 + ln;
    const int* nfr = nf + n * 9;
    float acc = 0.f;
#pragma unroll
    for (int c = 0; c < 9; ++c) {
        int idx = nfr[c];
        acc += emb[((c << 7) + idx) * 64 + d];
    }
    x[n * 64 + d] = acc;
    sx[ln][d] = acc;
    __syncthreads();
    if (d < 32) {
        float o = bias[d];
#pragma unroll
        for (int k = 0; k < 64; ++k) o += sx[ln][k] * root[k * 32 + d];
        out[n * 32 + d] = o;
    }
}

// ---------- h1[c,:] = relu(etab[c] @ gW1), etab computed in-LDS ----------
__global__ __launch_bounds__(256) void k_h1(
    const float* __restrict__ bemb, const float* __restrict__ gW1,
    float* __restrict__ h1) {
    __shared__ float se[16];
    const int b = blockIdx.x, t = threadIdx.x;
    const int c = b >> 2;
    const int n = ((b & 3) << 8) + t;
    if (t < 16) {
        int f0 = c >> 6, f1 = (c >> 3) & 7, f2 = c & 7;
        se[t] = bemb[f0 * 16 + t] + bemb[(8 + f1) * 16 + t] +
                bemb[(16 + f2) * 16 + t];
    }
    __syncthreads();
    float acc = 0.f;
#pragma unroll
    for (int k = 0; k < 16; ++k) acc += se[k] * gW1[k * 1024 + n];
    h1[c * 1024 + n] = fmaxf(acc, 0.f);
}

// ---------- tiled GEMM, 64x64 block tile, 4x4 micro tile, split-K over z ------
template <int BM, int BN, int BK, int TM, int TN>
__global__ __launch_bounds__(256)
void k_gemm_tiled(const float* __restrict__ A, const float* __restrict__ B,
                  const float* __restrict__ bias, float* __restrict__ C,
                  float* __restrict__ Cp, int M, int N, int K, int KS, int relu) {
    constexpr int TX = BN / TN;                 // 16
    constexpr int TY = BM / TM;                 // 16
    static_assert(TX * TY == 256, "block must be 256 threads");
    __shared__ float As[BK][BM + 4];            // transposed A tile
    __shared__ float Bs[BK][BN + 4];
    const int tx = threadIdx.x % TX, ty = threadIdx.x / TX;
    const int row0 = blockIdx.y * BM, col0 = blockIdx.x * BN;
    const int z = blockIdx.z;
    const int k_begin = z * KS, k_end = k_begin + KS;

    const int am = threadIdx.x >> 2;            // 0..63
    const int ak = (threadIdx.x & 3) << 2;      // 0,4,8,12
    const int bk = threadIdx.x >> 4;            // 0..15
    const int bn = (threadIdx.x & 15) << 2;     // 0..60

    float acc[TM][TN] = {};
    for (int k0 = k_begin; k0 < k_end; k0 += BK) {
        float4 av = *reinterpret_cast<const float4*>(&A[(row0 + am) * K + k0 + ak]);
        float4 bv = *reinterpret_cast<const float4*>(&B[(k0 + bk) * N + col0 + bn]);
        As[ak + 0][am] = av.x;
        As[ak + 1][am] = av.y;
        As[ak + 2][am] = av.z;
        As[ak + 3][am] = av.w;
        *reinterpret_cast<float4*>(&Bs[bk][bn]) = bv;
        __syncthreads();
#pragma unroll
        for (int k = 0; k < BK; ++k) {
            float a[TM], b[TN];
            *reinterpret_cast<float4*>(a) =
                *reinterpret_cast<const float4*>(&As[k][ty * TM]);
            *reinterpret_cast<float4*>(b) =
                *reinterpret_cast<const float4*>(&Bs[k][tx * TN]);
#pragma unroll
            for (int i = 0; i < TM; ++i)
#pragma unroll
                for (int j = 0; j < TN; ++j) acc[i][j] += a[i] * b[j];
        }
        __syncthreads();
    }

    const int MN = M * N;
    if (gridDim.z == 1) {
#pragma unroll
        for (int i = 0; i < TM; ++i) {
            int r = row0 + ty * TM + i;
            float4 v;
            v.x = acc[i][0]; v.y = acc[i][1]; v.z = acc[i][2]; v.w = acc[i][3];
            int c = col0 + tx * TN;
            if (bias) { v.x += bias[c]; v.y += bias[c+1]; v.z += bias[c+2]; v.w += bias[c+3]; }
            if (relu) { v.x = fmaxf(v.x,0.f); v.y = fmaxf(v.y,0.f);
                        v.z = fmaxf(v.z,0.f); v.w = fmaxf(v.w,0.f); }
            *reinterpret_cast<float4*>(&C[r * N + c]) = v;
        }
    } else {
        float* dstp = Cp + z * MN;
#pragma unroll
        for (int i = 0; i < TM; ++i) {
            int r = row0 + ty * TM + i;
            float4 v;
            v.x = acc[i][0]; v.y = acc[i][1]; v.z = acc[i][2]; v.w = acc[i][3];
            *reinterpret_cast<float4*>(&dstp[r * N + col0 + tx * TN]) = v;
        }
    }
}

// ---------- split-K reduce: C = relu?(sum_z Cp[z] + bias) ----------
__global__ void k_reduceK(const float* __restrict__ Cp, const float* __restrict__ bias,
                          float* __restrict__ C, int MN, int N, int nz, int relu) {
    int i4 = (blockIdx.x * 256 + threadIdx.x) * 4;
    if (i4 >= MN) return;
    float4 acc = *reinterpret_cast<const float4*>(&Cp[i4]);
    for (int z = 1; z < nz; ++z) {
        float4 t = *reinterpret_cast<const float4*>(&Cp[z * MN + i4]);
        acc.x += t.x; acc.y += t.y; acc.z += t.z; acc.w += t.w;
    }
    if (bias) {
        int c = i4 % N;
        acc.x += bias[c]; acc.y += bias[c + 1]; acc.z += bias[c + 2]; acc.w += bias[c + 3];
    }
    if (relu) {
        acc.x = fmaxf(acc.x, 0.f); acc.y = fmaxf(acc.y, 0.f);
        acc.z = fmaxf(acc.z, 0.f); acc.w = fmaxf(acc.w, 0.f);
    }
    *reinterpret_cast<float4*>(&C[i4]) = acc;
}

// ---------- NNConv message + scatter: TWO independent edge chains per thread -
// Thread (p, o) computes output col o for edges e0 = p and e1 = p + NEDGES/2.
// The two load streams are interleaved, independent named scalars (no arrays,
// no sinking): even a wait-per-use scheduler keeps 2 loads in flight,
// halving the serialized-gather latency chain that gates k_msg (~46 us).
// Coalescing identical to round-0 k_msg: lanes 0-31 read consecutive W floats.
__global__ void k_msg2(const float* __restrict__ x, const float* __restrict__ wtab,
                       const int* __restrict__ ef, const int* __restrict__ src,
                       const int* __restrict__ dst, float* __restrict__ out) {
    int gid = blockIdx.x * blockDim.x + threadIdx.x;   // (NEDGES/2)*32
    int e0 = gid >> 5, o = gid & 31;
    int e1 = e0 + NEDGES / 2;
    int s0 = src[e0], d0 = dst[e0];
    int s1 = src[e1], d1 = dst[e1];
    int c0 = (ef[e0 * 3] << 6) | (ef[e0 * 3 + 1] << 3) | ef[e0 * 3 + 2];
    int c1 = (ef[e1 * 3] << 6) | (ef[e1 * 3 + 1] << 3) | ef[e1 * 3 + 2];
    const float* xr0 = x + s0 * 64;
    const float* xr1 = x + s1 * 64;
    const float* w0 = wtab + c0 * 2048 + o;
    const float* w1 = wtab + c1 * 2048 + o;
    float a0 = 0.f, a1 = 0.f;
#pragma unroll
    for (int k = 0; k < 64; ++k) {
        a0 += xr0[k] * w0[k * 32];
        a1 += xr1[k] * w1[k * 32];
    }
    atomicAdd(&out[d0 * 32 + o], a0);
    atomicAdd(&out[d1 * 32 + o], a1);
}

// ---------- fused readout tail: f1 -> f2 -> f3 -> f4 -> out, 4 graphs/block --
__global__ __launch_bounds__(256) void k_tail2(
    const float* __restrict__ f1,
    const float* __restrict__ mW2, const float* __restrict__ mb2,
    const float* __restrict__ mW3, const float* __restrict__ mb3,
    const float* __restrict__ mW4, const float* __restrict__ mb4,
    const float* __restrict__ mW5, const float* __restrict__ mb5,
    float* __restrict__ outv) {
    __shared__ float s1[4][256];
    __shared__ float s2[4][128];
    __shared__ float s3[4][32];
    __shared__ float s4[4][8];
    const int t  = threadIdx.x;
    const int g0 = blockIdx.x * 4;
#pragma unroll
    for (int i = 0; i < 4; ++i) {
        int idx = t + i * 256;
        s1[idx >> 8][idx & 255] = f1[g0 * 256 + idx];
    }
    __syncthreads();
#pragma unroll
    for (int i = 0; i < 2; ++i) {
        int idx = t + i * 256;
        int g = idx >> 7, cc = idx & 127;
        float acc = mb2[cc];
#pragma unroll 8
        for (int k = 0; k < 256; ++k) acc += s1[g][k] * mW2[k * 128 + cc];
        s2[g][cc] = fmaxf(acc, 0.f);
    }
    __syncthreads();
    const int w = t >> 6, lane = t & 63;
    if (lane < 32) {
        float acc = mb3[lane];
#pragma unroll 8
        for (int k = 0; k < 128; ++k) acc += s2[w][k] * mW3[k * 32 + lane];
        s3[w][lane] = fmaxf(acc, 0.f);
    }
    __syncthreads();
    if (lane < 8) {
        float acc = mb4[lane];
#pragma unroll
        for (int k = 0; k < 32; ++k) acc += s3[w][k] * mW4[k * 8 + lane];
        s4[w][lane] = fmaxf(acc, 0.f);
    }
    __syncthreads();
    if (lane == 0) {
        float acc = mb5[0];
#pragma unroll
        for (int k = 0; k < 8; ++k) acc += s4[w][k] * mW5[k];
        outv[g0 + w] = acc;
    }
}

extern "C" void kernel_launch(void* const* d_in, const int* in_sizes, int n_in,
                              void* d_out, int out_size, void* d_ws, size_t ws_size,
                              hipStream_t stream) {
    const int*   nf      = (const int*)d_in[0];
    const int*   ef      = (const int*)d_in[1];
    const int*   eidx    = (const int*)d_in[2];
    const float* atom_emb= (const float*)d_in[4];
    const float* bond_emb= (const float*)d_in[5];
    const float* gW1     = (const float*)d_in[6];
    const float* gW2     = (const float*)d_in[7];
    const float* gW3     = (const float*)d_in[8];
    const float* root    = (const float*)d_in[9];
    const float* cbias   = (const float*)d_in[10];
    const float* mW1     = (const float*)d_in[11];
    const float* mb1     = (const float*)d_in[12];
    const float* mW2     = (const float*)d_in[13];
    const float* mb2     = (const float*)d_in[14];
    const float* mW3     = (const float*)d_in[15];
    const float* mb3     = (const float*)d_in[16];
    const float* mW4     = (const float*)d_in[17];
    const float* mb4     = (const float*)d_in[18];
    const float* mW5     = (const float*)d_in[19];
    const float* mb5     = (const float*)d_in[20];

    const int* src = eidx;
    const int* dst = eidx + NEDGES;

    float* ws = (float*)d_ws;
    float* x    = ws;                        // 40960*64   = 2621440
    float* out  = x + 2621440;               // 40960*32   = 1310720
    float* h1   = out + 1310720;             // 512*1024   = 524288
    float* h2   = h1 + 524288;               // 512*256    = 131072
    float* wtab = h2 + 131072;               // 512*2048   = 1048576
    float* f1   = wtab + 1048576;            // 1024*256   = 262144
    float* part = f1 + 262144;               // 2097152 (8 MB split-K partials)

    // 1. fused atom encoder + root transform
    k_node<<<NNODES / 4, 256, 0, stream>>>(nf, atom_emb, root, cbias, x, out);
    // 2. h1 = relu(etab @ gW1), etab computed in-LDS per block
    k_h1<<<NCOMBO * 4, 256, 0, stream>>>(bond_emb, gW1, h1);
    // 3. h2 = relu(h1 @ gW2): 512x256, K=1024, split 16x64
    k_gemm_tiled<64, 64, 16, 4, 4><<<dim3(4, 8, 16), 256, 0, stream>>>(
        h1, gW2, nullptr, nullptr, part, NCOMBO, 256, 1024, 64, 0);
    k_reduceK<<<131072 / 1024, 256, 0, stream>>>(part, nullptr, h2, 131072, 256, 16, 1);
    // 4. wtab = h2 @ gW3: 512x2048, K=256, split 2x128
    k_gemm_tiled<64, 64, 16, 4, 4><<<dim3(32, 8, 2), 256, 0, stream>>>(
        h2, gW3, nullptr, nullptr, part, NCOMBO, 2048, 256, 128, 0);
    k_reduceK<<<1048576 / 1024, 256, 0, stream>>>(part, nullptr, wtab, 1048576, 2048, 2, 0);
    // 5. per-edge message + scatter: 2 independent edge chains per thread
    k_msg2<<<(NEDGES / 2) * 32 / 256, 256, 0, stream>>>(x, wtab, ef, src, dst, out);
    // 6. f1 = relu(dense @ mW1 + mb1): 1024x256, K=1280, split 8x160
    k_gemm_tiled<64, 64, 16, 4, 4><<<dim3(4, 16, 8), 256, 0, stream>>>(
        out, mW1, nullptr, nullptr, part, NG, 256, 1280, 160, 0);
    k_reduceK<<<262144 / 1024, 256, 0, stream>>>(part, mb1, f1, 262144, 256, 8, 1);
    // 7. fused tail: f2, f3, f4, final
    k_tail2<<<NG / 4, 256, 0, stream>>>(f1, mW2, mb2, mW3, mb3, mW4, mb4,
                                        mW5, mb5, (float*)d_out);
}

// Round 16
// 226.899 us; speedup vs baseline: 1.3259x; 1.0311x over previous
//
#include <hip/hip_runtime.h>

#define NNODES 40960
#define NEDGES 81920
#define NG     1024
#define NCOMBO 512

// ---- inline-asm W-load pipeline helpers (compiler cannot re-serialize) ----
#define ISSUE_LO(w, p) asm volatile( \
  "global_load_dword %0, %16, off\n\t" \
  "global_load_dword %1, %16, off offset:128\n\t" \
  "global_load_dword %2, %16, off offset:256\n\t" \
  "global_load_dword %3, %16, off offset:384\n\t" \
  "global_load_dword %4, %16, off offset:512\n\t" \
  "global_load_dword %5, %16, off offset:640\n\t" \
  "global_load_dword %6, %16, off offset:768\n\t" \
  "global_load_dword %7, %16, off offset:896\n\t" \
  "global_load_dword %8, %16, off offset:1024\n\t" \
  "global_load_dword %9, %16, off offset:1152\n\t" \
  "global_load_dword %10, %16, off offset:1280\n\t" \
  "global_load_dword %11, %16, off offset:1408\n\t" \
  "global_load_dword %12, %16, off offset:1536\n\t" \
  "global_load_dword %13, %16, off offset:1664\n\t" \
  "global_load_dword %14, %16, off offset:1792\n\t" \
  "global_load_dword %15, %16, off offset:1920\n\t" \
  : "=v"(w[0]),"=v"(w[1]),"=v"(w[2]),"=v"(w[3]),"=v"(w[4]),"=v"(w[5]), \
    "=v"(w[6]),"=v"(w[7]),"=v"(w[8]),"=v"(w[9]),"=v"(w[10]),"=v"(w[11]), \
    "=v"(w[12]),"=v"(w[13]),"=v"(w[14]),"=v"(w[15]) \
  : "v"(p))

#define ISSUE_HI(w, p) asm volatile( \
  "global_load_dword %0, %16, off offset:2048\n\t" \
  "global_load_dword %1, %16, off offset:2176\n\t" \
  "global_load_dword %2, %16, off offset:2304\n\t" \
  "global_load_dword %3, %16, off offset:2432\n\t" \
  "global_load_dword %4, %16, off offset:2560\n\t" \
  "global_load_dword %5, %16, off offset:2688\n\t" \
  "global_load_dword %6, %16, off offset:2816\n\t" \
  "global_load_dword %7, %16, off offset:2944\n\t" \
  "global_load_dword %8, %16, off offset:3072\n\t" \
  "global_load_dword %9, %16, off offset:3200\n\t" \
  "global_load_dword %10, %16, off offset:3328\n\t" \
  "global_load_dword %11, %16, off offset:3456\n\t" \
  "global_load_dword %12, %16, off offset:3584\n\t" \
  "global_load_dword %13, %16, off offset:3712\n\t" \
  "global_load_dword %14, %16, off offset:3840\n\t" \
  "global_load_dword %15, %16, off offset:3968\n\t" \
  : "=v"(w[0]),"=v"(w[1]),"=v"(w[2]),"=v"(w[3]),"=v"(w[4]),"=v"(w[5]), \
    "=v"(w[6]),"=v"(w[7]),"=v"(w[8]),"=v"(w[9]),"=v"(w[10]),"=v"(w[11]), \
    "=v"(w[12]),"=v"(w[13]),"=v"(w[14]),"=v"(w[15]) \
  : "v"(p))

// counted wait; batch values threaded through as "+v" so consuming FMAs
// carry a data dependency on this block (cannot be hoisted above it).
#define WAIT16(N, w) asm volatile("s_waitcnt vmcnt(" #N ")" \
  : "+v"(w[0]),"+v"(w[1]),"+v"(w[2]),"+v"(w[3]),"+v"(w[4]),"+v"(w[5]), \
    "+v"(w[6]),"+v"(w[7]),"+v"(w[8]),"+v"(w[9]),"+v"(w[10]),"+v"(w[11]), \
    "+v"(w[12]),"+v"(w[13]),"+v"(w[14]),"+v"(w[15]))

// ---------- fused node encoder: x[n,:], then out_init[n,:] = bias + x@root ---
__global__ __launch_bounds__(256) void k_node(
    const int* __restrict__ nf, const float* __restrict__ emb,
    const float* __restrict__ root, const float* __restrict__ bias,
    float* __restrict__ x, float* __restrict__ out) {
    __shared__ float sx[4][64];
    const int t = threadIdx.x;
    const int ln = t >> 6;                 // local node 0..3
    const int d  = t & 63;
    const int n  = blockIdx.x * 4 + ln;
    const int* nfr = nf + n * 9;
    float acc = 0.f;
#pragma unroll
    for (int c = 0; c < 9; ++c) {
        int idx = nfr[c];
        acc += emb[((c << 7) + idx) * 64 + d];
    }
    x[n * 64 + d] = acc;
    sx[ln][d] = acc;
    __syncthreads();
    if (d < 32) {
        float o = bias[d];
#pragma unroll
        for (int k = 0; k < 64; ++k) o += sx[ln][k] * root[k * 32 + d];
        out[n * 32 + d] = o;
    }
}

// ---------- h1[c,:] = relu(etab[c] @ gW1), etab computed in-LDS ----------
__global__ __launch_bounds__(256) void k_h1(
    const float* __restrict__ bemb, const float* __restrict__ gW1,
    float* __restrict__ h1) {
    __shared__ float se[16];
    const int b = blockIdx.x, t = threadIdx.x;
    const int c = b >> 2;
    const int n = ((b & 3) << 8) + t;
    if (t < 16) {
        int f0 = c >> 6, f1 = (c >> 3) & 7, f2 = c & 7;
        se[t] = bemb[f0 * 16 + t] + bemb[(8 + f1) * 16 + t] +
                bemb[(16 + f2) * 16 + t];
    }
    __syncthreads();
    float acc = 0.f;
#pragma unroll
    for (int k = 0; k < 16; ++k) acc += se[k] * gW1[k * 1024 + n];
    h1[c * 1024 + n] = fmaxf(acc, 0.f);
}

// ---------- tiled GEMM, 64x64 block tile, 4x4 micro tile, split-K over z ------
template <int BM, int BN, int BK, int TM, int TN>
__global__ __launch_bounds__(256)
void k_gemm_tiled(const float* __restrict__ A, const float* __restrict__ B,
                  const float* __restrict__ bias, float* __restrict__ C,
                  float* __restrict__ Cp, int M, int N, int K, int KS, int relu) {
    constexpr int TX = BN / TN;                 // 16
    constexpr int TY = BM / TM;                 // 16
    static_assert(TX * TY == 256, "block must be 256 threads");
    __shared__ float As[BK][BM + 4];            // transposed A tile
    __shared__ float Bs[BK][BN + 4];
    const int tx = threadIdx.x % TX, ty = threadIdx.x / TX;
    const int row0 = blockIdx.y * BM, col0 = blockIdx.x * BN;
    const int z = blockIdx.z;
    const int k_begin = z * KS, k_end = k_begin + KS;

    const int am = threadIdx.x >> 2;            // 0..63
    const int ak = (threadIdx.x & 3) << 2;      // 0,4,8,12
    const int bk = threadIdx.x >> 4;            // 0..15
    const int bn = (threadIdx.x & 15) << 2;     // 0..60

    float acc[TM][TN] = {};
    for (int k0 = k_begin; k0 < k_end; k0 += BK) {
        float4 av = *reinterpret_cast<const float4*>(&A[(row0 + am) * K + k0 + ak]);
        float4 bv = *reinterpret_cast<const float4*>(&B[(k0 + bk) * N + col0 + bn]);
        As[ak + 0][am] = av.x;
        As[ak + 1][am] = av.y;
        As[ak + 2][am] = av.z;
        As[ak + 3][am] = av.w;
        *reinterpret_cast<float4*>(&Bs[bk][bn]) = bv;
        __syncthreads();
#pragma unroll
        for (int k = 0; k < BK; ++k) {
            float a[TM], b[TN];
            *reinterpret_cast<float4*>(a) =
                *reinterpret_cast<const float4*>(&As[k][ty * TM]);
            *reinterpret_cast<float4*>(b) =
                *reinterpret_cast<const float4*>(&Bs[k][tx * TN]);
#pragma unroll
            for (int i = 0; i < TM; ++i)
#pragma unroll
                for (int j = 0; j < TN; ++j) acc[i][j] += a[i] * b[j];
        }
        __syncthreads();
    }

    const int MN = M * N;
    if (gridDim.z == 1) {
#pragma unroll
        for (int i = 0; i < TM; ++i) {
            int r = row0 + ty * TM + i;
            float4 v;
            v.x = acc[i][0]; v.y = acc[i][1]; v.z = acc[i][2]; v.w = acc[i][3];
            int c = col0 + tx * TN;
            if (bias) { v.x += bias[c]; v.y += bias[c+1]; v.z += bias[c+2]; v.w += bias[c+3]; }
            if (relu) { v.x = fmaxf(v.x,0.f); v.y = fmaxf(v.y,0.f);
                        v.z = fmaxf(v.z,0.f); v.w = fmaxf(v.w,0.f); }
            *reinterpret_cast<float4*>(&C[r * N + c]) = v;
        }
    } else {
        float* dstp = Cp + z * MN;
#pragma unroll
        for (int i = 0; i < TM; ++i) {
            int r = row0 + ty * TM + i;
            float4 v;
            v.x = acc[i][0]; v.y = acc[i][1]; v.z = acc[i][2]; v.w = acc[i][3];
            *reinterpret_cast<float4*>(&dstp[r * N + col0 + tx * TN]) = v;
        }
    }
}

// ---------- split-K reduce: C = relu?(sum_z Cp[z] + bias) ----------
__global__ void k_reduceK(const float* __restrict__ Cp, const float* __restrict__ bias,
                          float* __restrict__ C, int MN, int N, int nz, int relu) {
    int i4 = (blockIdx.x * 256 + threadIdx.x) * 4;
    if (i4 >= MN) return;
    float4 acc = *reinterpret_cast<const float4*>(&Cp[i4]);
    for (int z = 1; z < nz; ++z) {
        float4 t = *reinterpret_cast<const float4*>(&Cp[z * MN + i4]);
        acc.x += t.x; acc.y += t.y; acc.z += t.z; acc.w += t.w;
    }
    if (bias) {
        int c = i4 % N;
        acc.x += bias[c]; acc.y += bias[c + 1]; acc.z += bias[c + 2]; acc.w += bias[c + 3];
    }
    if (relu) {
        acc.x = fmaxf(acc.x, 0.f); acc.y = fmaxf(acc.y, 0.f);
        acc.z = fmaxf(acc.z, 0.f); acc.w = fmaxf(acc.w, 0.f);
    }
    *reinterpret_cast<float4*>(&C[i4]) = acc;
}

// ---------- NNConv message + scatter: asm-pipelined W loads ----------
// Block = 8 edges x 32 cols. x rows staged in LDS (lgkmcnt domain, keeps
// vmcnt bookkeeping exact). 64 W loads issued as 4 x 16-load asm batches
// with counted vmcnt waits (48 in flight peak). FMA order = k ascending,
// bit-identical to round-9 k_msg. Atomic scatter unchanged.
__global__ __launch_bounds__(256) void k_msga(
    const float* __restrict__ x, const float* __restrict__ wtab,
    const int* __restrict__ ef, const int* __restrict__ src,
    const int* __restrict__ dst, float* __restrict__ out) {
    __shared__ float sx[8][64];
    const int t = threadIdx.x;
    const int e_base = blockIdx.x * 8;
    {   // cooperative x staging: 8 rows x 64 floats, 2 per thread
        int idx = t;
        int r = idx >> 6, cl = idx & 63;
        sx[r][cl] = x[src[e_base + r] * 64 + cl];
        idx = t + 256;
        r = idx >> 6; cl = idx & 63;
        sx[r][cl] = x[src[e_base + r] * 64 + cl];
    }
    const int slot = t >> 5, o = t & 31;
    const int e = e_base + slot;
    const int d = dst[e];
    const int c = (ef[e * 3] << 6) | (ef[e * 3 + 1] << 3) | ef[e * 3 + 2];
    const float* wl = wtab + c * 2048 + o;     // k=0..31 at byte offsets k*128
    const float* wh = wl + 1024;               // k=32..63
    __syncthreads();                           // drains all prior vmcnt/lgkmcnt

    float wA[16], wB[16], wC[16], wD[16];
    ISSUE_LO(wA, wl);                          // b0: k 0..15   (16 in flight)
    ISSUE_HI(wB, wl);                          // b1: k 16..31  (32)
    ISSUE_LO(wC, wh);                          // b2: k 32..47  (48)
    float acc = 0.f;
    WAIT16(32, wA);                            // b0 complete
    ISSUE_HI(wD, wh);                          // b3: k 48..63  (<=48)
#pragma unroll
    for (int i = 0; i < 16; ++i) acc += sx[slot][i] * wA[i];
    WAIT16(32, wB);                            // b1 complete
#pragma unroll
    for (int i = 0; i < 16; ++i) acc += sx[slot][16 + i] * wB[i];
    WAIT16(16, wC);                            // b2 complete
#pragma unroll
    for (int i = 0; i < 16; ++i) acc += sx[slot][32 + i] * wC[i];
    WAIT16(0, wD);                             // b3 complete
#pragma unroll
    for (int i = 0; i < 16; ++i) acc += sx[slot][48 + i] * wD[i];
    atomicAdd(&out[d * 32 + o], acc);
}

// ---------- fused readout tail: f1 -> f2 -> f3 -> f4 -> out, 4 graphs/block --
__global__ __launch_bounds__(256) void k_tail2(
    const float* __restrict__ f1,
    const float* __restrict__ mW2, const float* __restrict__ mb2,
    const float* __restrict__ mW3, const float* __restrict__ mb3,
    const float* __restrict__ mW4, const float* __restrict__ mb4,
    const float* __restrict__ mW5, const float* __restrict__ mb5,
    float* __restrict__ outv) {
    __shared__ float s1[4][256];
    __shared__ float s2[4][128];
    __shared__ float s3[4][32];
    __shared__ float s4[4][8];
    const int t  = threadIdx.x;
    const int g0 = blockIdx.x * 4;
#pragma unroll
    for (int i = 0; i < 4; ++i) {
        int idx = t + i * 256;
        s1[idx >> 8][idx & 255] = f1[g0 * 256 + idx];
    }
    __syncthreads();
#pragma unroll
    for (int i = 0; i < 2; ++i) {
        int idx = t + i * 256;
        int g = idx >> 7, cc = idx & 127;
        float acc = mb2[cc];
#pragma unroll 8
        for (int k = 0; k < 256; ++k) acc += s1[g][k] * mW2[k * 128 + cc];
        s2[g][cc] = fmaxf(acc, 0.f);
    }
    __syncthreads();
    const int w = t >> 6, lane = t & 63;
    if (lane < 32) {
        float acc = mb3[lane];
#pragma unroll 8
        for (int k = 0; k < 128; ++k) acc += s2[w][k] * mW3[k * 32 + lane];
        s3[w][lane] = fmaxf(acc, 0.f);
    }
    __syncthreads();
    if (lane < 8) {
        float acc = mb4[lane];
#pragma unroll
        for (int k = 0; k < 32; ++k) acc += s3[w][k] * mW4[k * 8 + lane];
        s4[w][lane] = fmaxf(acc, 0.f);
    }
    __syncthreads();
    if (lane == 0) {
        float acc = mb5[0];
#pragma unroll
        for (int k = 0; k < 8; ++k) acc += s4[w][k] * mW5[k];
        outv[g0 + w] = acc;
    }
}

extern "C" void kernel_launch(void* const* d_in, const int* in_sizes, int n_in,
                              void* d_out, int out_size, void* d_ws, size_t ws_size,
                              hipStream_t stream) {
    const int*   nf      = (const int*)d_in[0];
    const int*   ef      = (const int*)d_in[1];
    const int*   eidx    = (const int*)d_in[2];
    const float* atom_emb= (const float*)d_in[4];
    const float* bond_emb= (const float*)d_in[5];
    const float* gW1     = (const float*)d_in[6];
    const float* gW2     = (const float*)d_in[7];
    const float* gW3     = (const float*)d_in[8];
    const float* root    = (const float*)d_in[9];
    const float* cbias   = (const float*)d_in[10];
    const float* mW1     = (const float*)d_in[11];
    const float* mb1     = (const float*)d_in[12];
    const float* mW2     = (const float*)d_in[13];
    const float* mb2     = (const float*)d_in[14];
    const float* mW3     = (const float*)d_in[15];
    const float* mb3     = (const float*)d_in[16];
    const float* mW4     = (const float*)d_in[17];
    const float* mb4     = (const float*)d_in[18];
    const float* mW5     = (const float*)d_in[19];
    const float* mb5     = (const float*)d_in[20];

    const int* src = eidx;
    const int* dst = eidx + NEDGES;

    float* ws = (float*)d_ws;
    float* x    = ws;                        // 40960*64   = 2621440
    float* out  = x + 2621440;               // 40960*32   = 1310720
    float* h1   = out + 1310720;             // 512*1024   = 524288
    float* h2   = h1 + 524288;               // 512*256    = 131072
    float* wtab = h2 + 131072;               // 512*2048   = 1048576
    float* f1   = wtab + 1048576;            // 1024*256   = 262144
    float* part = f1 + 262144;               // 2097152 (8 MB split-K partials)

    // 1. fused atom encoder + root transform
    k_node<<<NNODES / 4, 256, 0, stream>>>(nf, atom_emb, root, cbias, x, out);
    // 2. h1 = relu(etab @ gW1), etab computed in-LDS per block
    k_h1<<<NCOMBO * 4, 256, 0, stream>>>(bond_emb, gW1, h1);
    // 3. h2 = relu(h1 @ gW2): 512x256, K=1024, split 16x64
    k_gemm_tiled<64, 64, 16, 4, 4><<<dim3(4, 8, 16), 256, 0, stream>>>(
        h1, gW2, nullptr, nullptr, part, NCOMBO, 256, 1024, 64, 0);
    k_reduceK<<<131072 / 1024, 256, 0, stream>>>(part, nullptr, h2, 131072, 256, 16, 1);
    // 4. wtab = h2 @ gW3: 512x2048, K=256, split 2x128
    k_gemm_tiled<64, 64, 16, 4, 4><<<dim3(32, 8, 2), 256, 0, stream>>>(
        h2, gW3, nullptr, nullptr, part, NCOMBO, 2048, 256, 128, 0);
    k_reduceK<<<1048576 / 1024, 256, 0, stream>>>(part, nullptr, wtab, 1048576, 2048, 2, 0);
    // 5. per-edge message + scatter: asm-pipelined W loads (counted vmcnt)
    k_msga<<<NEDGES / 8, 256, 0, stream>>>(x, wtab, ef, src, dst, out);
    // 6. f1 = relu(dense @ mW1 + mb1): 1024x256, K=1280, split 8x160
    k_gemm_tiled<64, 64, 16, 4, 4><<<dim3(4, 16, 8), 256, 0, stream>>>(
        out, mW1, nullptr, nullptr, part, NG, 256, 1280, 160, 0);
    k_reduceK<<<262144 / 1024, 256, 0, stream>>>(part, mb1, f1, 262144, 256, 8, 1);
    // 7. fused tail: f2, f3, f4, final
    k_tail2<<<NG / 4, 256, 0, stream>>>(f1, mW2, mb2, mW3, mb3, mW4, mb4,
                                        mW5, mb5, (float*)d_out);
}

// Round 18
// 223.780 us; speedup vs baseline: 1.3444x; 1.0139x over previous
//
#include <hip/hip_runtime.h>

#define NNODES 40960
#define NEDGES 81920
#define NG     1024
#define NCOMBO 512

// ---- inline-asm W-load pipeline helpers (compiler cannot re-serialize) ----
#define ISSUE_LO(w, p) asm volatile( \
  "global_load_dword %0, %16, off\n\t" \
  "global_load_dword %1, %16, off offset:128\n\t" \
  "global_load_dword %2, %16, off offset:256\n\t" \
  "global_load_dword %3, %16, off offset:384\n\t" \
  "global_load_dword %4, %16, off offset:512\n\t" \
  "global_load_dword %5, %16, off offset:640\n\t" \
  "global_load_dword %6, %16, off offset:768\n\t" \
  "global_load_dword %7, %16, off offset:896\n\t" \
  "global_load_dword %8, %16, off offset:1024\n\t" \
  "global_load_dword %9, %16, off offset:1152\n\t" \
  "global_load_dword %10, %16, off offset:1280\n\t" \
  "global_load_dword %11, %16, off offset:1408\n\t" \
  "global_load_dword %12, %16, off offset:1536\n\t" \
  "global_load_dword %13, %16, off offset:1664\n\t" \
  "global_load_dword %14, %16, off offset:1792\n\t" \
  "global_load_dword %15, %16, off offset:1920\n\t" \
  : "=v"(w[0]),"=v"(w[1]),"=v"(w[2]),"=v"(w[3]),"=v"(w[4]),"=v"(w[5]), \
    "=v"(w[6]),"=v"(w[7]),"=v"(w[8]),"=v"(w[9]),"=v"(w[10]),"=v"(w[11]), \
    "=v"(w[12]),"=v"(w[13]),"=v"(w[14]),"=v"(w[15]) \
  : "v"(p))

#define ISSUE_HI(w, p) asm volatile( \
  "global_load_dword %0, %16, off offset:2048\n\t" \
  "global_load_dword %1, %16, off offset:2176\n\t" \
  "global_load_dword %2, %16, off offset:2304\n\t" \
  "global_load_dword %3, %16, off offset:2432\n\t" \
  "global_load_dword %4, %16, off offset:2560\n\t" \
  "global_load_dword %5, %16, off offset:2688\n\t" \
  "global_load_dword %6, %16, off offset:2816\n\t" \
  "global_load_dword %7, %16, off offset:2944\n\t" \
  "global_load_dword %8, %16, off offset:3072\n\t" \
  "global_load_dword %9, %16, off offset:3200\n\t" \
  "global_load_dword %10, %16, off offset:3328\n\t" \
  "global_load_dword %11, %16, off offset:3456\n\t" \
  "global_load_dword %12, %16, off offset:3584\n\t" \
  "global_load_dword %13, %16, off offset:3712\n\t" \
  "global_load_dword %14, %16, off offset:3840\n\t" \
  "global_load_dword %15, %16, off offset:3968\n\t" \
  : "=v"(w[0]),"=v"(w[1]),"=v"(w[2]),"=v"(w[3]),"=v"(w[4]),"=v"(w[5]), \
    "=v"(w[6]),"=v"(w[7]),"=v"(w[8]),"=v"(w[9]),"=v"(w[10]),"=v"(w[11]), \
    "=v"(w[12]),"=v"(w[13]),"=v"(w[14]),"=v"(w[15]) \
  : "v"(p))

// counted wait; batch values threaded through as "+v" so consuming FMAs
// carry a data dependency on this block (cannot be hoisted above it).
#define WAIT16(N, w) asm volatile("s_waitcnt vmcnt(" #N ")" \
  : "+v"(w[0]),"+v"(w[1]),"+v"(w[2]),"+v"(w[3]),"+v"(w[4]),"+v"(w[5]), \
    "+v"(w[6]),"+v"(w[7]),"+v"(w[8]),"+v"(w[9]),"+v"(w[10]),"+v"(w[11]), \
    "+v"(w[12]),"+v"(w[13]),"+v"(w[14]),"+v"(w[15]))

// ---------- fused node encoder: x[n,:], then out_init[n,:] = bias + x@root ---
__global__ __launch_bounds__(256) void k_node(
    const int* __restrict__ nf, const float* __restrict__ emb,
    const float* __restrict__ root, const float* __restrict__ bias,
    float* __restrict__ x, float* __restrict__ out) {
    __shared__ float sx[4][64];
    const int t = threadIdx.x;
    const int ln = t >> 6;                 // local node 0..3
    const int d  = t & 63;
    const int n  = blockIdx.x * 4 + ln;
    const int* nfr = nf + n * 9;
    float acc = 0.f;
#pragma unroll
    for (int c = 0; c < 9; ++c) {
        int idx = nfr[c];
        acc += emb[((c << 7) + idx) * 64 + d];
    }
    x[n * 64 + d] = acc;
    sx[ln][d] = acc;
    __syncthreads();
    if (d < 32) {
        float o = bias[d];
#pragma unroll
        for (int k = 0; k < 64; ++k) o += sx[ln][k] * root[k * 32 + d];
        out[n * 32 + d] = o;
    }
}

// ---------- h1[c,:] = relu(etab[c] @ gW1), etab computed in-LDS ----------
__global__ __launch_bounds__(256) void k_h1(
    const float* __restrict__ bemb, const float* __restrict__ gW1,
    float* __restrict__ h1) {
    __shared__ float se[16];
    const int b = blockIdx.x, t = threadIdx.x;
    const int c = b >> 2;
    const int n = ((b & 3) << 8) + t;
    if (t < 16) {
        int f0 = c >> 6, f1 = (c >> 3) & 7, f2 = c & 7;
        se[t] = bemb[f0 * 16 + t] + bemb[(8 + f1) * 16 + t] +
                bemb[(16 + f2) * 16 + t];
    }
    __syncthreads();
    float acc = 0.f;
#pragma unroll
    for (int k = 0; k < 16; ++k) acc += se[k] * gW1[k * 1024 + n];
    h1[c * 1024 + n] = fmaxf(acc, 0.f);
}

// ---------- tiled GEMM, 64x64 block tile, 4x4 micro tile, split-K over z ------
template <int BM, int BN, int BK, int TM, int TN>
__global__ __launch_bounds__(256)
void k_gemm_tiled(const float* __restrict__ A, const float* __restrict__ B,
                  const float* __restrict__ bias, float* __restrict__ C,
                  float* __restrict__ Cp, int M, int N, int K, int KS, int relu) {
    constexpr int TX = BN / TN;                 // 16
    constexpr int TY = BM / TM;                 // 16
    static_assert(TX * TY == 256, "block must be 256 threads");
    __shared__ float As[BK][BM + 4];            // transposed A tile
    __shared__ float Bs[BK][BN + 4];
    const int tx = threadIdx.x % TX, ty = threadIdx.x / TX;
    const int row0 = blockIdx.y * BM, col0 = blockIdx.x * BN;
    const int z = blockIdx.z;
    const int k_begin = z * KS, k_end = k_begin + KS;

    const int am = threadIdx.x >> 2;            // 0..63
    const int ak = (threadIdx.x & 3) << 2;      // 0,4,8,12
    const int bk = threadIdx.x >> 4;            // 0..15
    const int bn = (threadIdx.x & 15) << 2;     // 0..60

    float acc[TM][TN] = {};
    for (int k0 = k_begin; k0 < k_end; k0 += BK) {
        float4 av = *reinterpret_cast<const float4*>(&A[(row0 + am) * K + k0 + ak]);
        float4 bv = *reinterpret_cast<const float4*>(&B[(k0 + bk) * N + col0 + bn]);
        As[ak + 0][am] = av.x;
        As[ak + 1][am] = av.y;
        As[ak + 2][am] = av.z;
        As[ak + 3][am] = av.w;
        *reinterpret_cast<float4*>(&Bs[bk][bn]) = bv;
        __syncthreads();
#pragma unroll
        for (int k = 0; k < BK; ++k) {
            float a[TM], b[TN];
            *reinterpret_cast<float4*>(a) =
                *reinterpret_cast<const float4*>(&As[k][ty * TM]);
            *reinterpret_cast<float4*>(b) =
                *reinterpret_cast<const float4*>(&Bs[k][tx * TN]);
#pragma unroll
            for (int i = 0; i < TM; ++i)
#pragma unroll
                for (int j = 0; j < TN; ++j) acc[i][j] += a[i] * b[j];
        }
        __syncthreads();
    }

    const int MN = M * N;
    if (gridDim.z == 1) {
#pragma unroll
        for (int i = 0; i < TM; ++i) {
            int r = row0 + ty * TM + i;
            float4 v;
            v.x = acc[i][0]; v.y = acc[i][1]; v.z = acc[i][2]; v.w = acc[i][3];
            int c = col0 + tx * TN;
            if (bias) { v.x += bias[c]; v.y += bias[c+1]; v.z += bias[c+2]; v.w += bias[c+3]; }
            if (relu) { v.x = fmaxf(v.x,0.f); v.y = fmaxf(v.y,0.f);
                        v.z = fmaxf(v.z,0.f); v.w = fmaxf(v.w,0.f); }
            *reinterpret_cast<float4*>(&C[r * N + c]) = v;
        }
    } else {
        float* dstp = Cp + z * MN;
#pragma unroll
        for (int i = 0; i < TM; ++i) {
            int r = row0 + ty * TM + i;
            float4 v;
            v.x = acc[i][0]; v.y = acc[i][1]; v.z = acc[i][2]; v.w = acc[i][3];
            *reinterpret_cast<float4*>(&dstp[r * N + col0 + tx * TN]) = v;
        }
    }
}

// ---------- split-K reduce: C = relu?(sum_z Cp[z] + bias) ----------
__global__ void k_reduceK(const float* __restrict__ Cp, const float* __restrict__ bias,
                          float* __restrict__ C, int MN, int N, int nz, int relu) {
    int i4 = (blockIdx.x * 256 + threadIdx.x) * 4;
    if (i4 >= MN) return;
    float4 acc = *reinterpret_cast<const float4*>(&Cp[i4]);
    for (int z = 1; z < nz; ++z) {
        float4 t = *reinterpret_cast<const float4*>(&Cp[z * MN + i4]);
        acc.x += t.x; acc.y += t.y; acc.z += t.z; acc.w += t.w;
    }
    if (bias) {
        int c = i4 % N;
        acc.x += bias[c]; acc.y += bias[c + 1]; acc.z += bias[c + 2]; acc.w += bias[c + 3];
    }
    if (relu) {
        acc.x = fmaxf(acc.x, 0.f); acc.y = fmaxf(acc.y, 0.f);
        acc.z = fmaxf(acc.z, 0.f); acc.w = fmaxf(acc.w, 0.f);
    }
    *reinterpret_cast<float4*>(&C[i4]) = acc;
}

// ---------- NNConv message + scatter: asm-pipelined W loads ----------
// Block = 8 edges x 32 cols. x rows staged in LDS (lgkmcnt domain, keeps
// vmcnt bookkeeping exact). 64 W loads issued as 4 x 16-load asm batches
// with counted vmcnt waits (48 in flight peak). FMA order = k ascending,
// bit-identical to round-9 k_msg. Atomic scatter unchanged.
// NOTE: this register budget (4 x 16 arrays + 2 pointer pairs) is verified
// to allocate without copies/spills of in-flight load destinations (r16).
// The 2-edge deepening (r17) exceeded it and crashed — do not extend.
__global__ __launch_bounds__(256) void k_msga(
    const float* __restrict__ x, const float* __restrict__ wtab,
    const int* __restrict__ ef, const int* __restrict__ src,
    const int* __restrict__ dst, float* __restrict__ out) {
    __shared__ float sx[8][64];
    const int t = threadIdx.x;
    const int e_base = blockIdx.x * 8;
    {   // cooperative x staging: 8 rows x 64 floats, 2 per thread
        int idx = t;
        int r = idx >> 6, cl = idx & 63;
        sx[r][cl] = x[src[e_base + r] * 64 + cl];
        idx = t + 256;
        r = idx >> 6; cl = idx & 63;
        sx[r][cl] = x[src[e_base + r] * 64 + cl];
    }
    const int slot = t >> 5, o = t & 31;
    const int e = e_base + slot;
    const int d = dst[e];
    const int c = (ef[e * 3] << 6) | (ef[e * 3 + 1] << 3) | ef[e * 3 + 2];
    const float* wl = wtab + c * 2048 + o;     // k=0..31 at byte offsets k*128
    const float* wh = wl + 1024;               // k=32..63
    __syncthreads();                           // drains all prior vmcnt/lgkmcnt

    float wA[16], wB[16], wC[16], wD[16];
    ISSUE_LO(wA, wl);                          // b0: k 0..15   (16 in flight)
    ISSUE_HI(wB, wl);                          // b1: k 16..31  (32)
    ISSUE_LO(wC, wh);                          // b2: k 32..47  (48)
    float acc = 0.f;
    WAIT16(32, wA);                            // b0 complete
    ISSUE_HI(wD, wh);                          // b3: k 48..63  (<=48)
#pragma unroll
    for (int i = 0; i < 16; ++i) acc += sx[slot][i] * wA[i];
    WAIT16(32, wB);                            // b1 complete
#pragma unroll
    for (int i = 0; i < 16; ++i) acc += sx[slot][16 + i] * wB[i];
    WAIT16(16, wC);                            // b2 complete
#pragma unroll
    for (int i = 0; i < 16; ++i) acc += sx[slot][32 + i] * wC[i];
    WAIT16(0, wD);                             // b3 complete
#pragma unroll
    for (int i = 0; i < 16; ++i) acc += sx[slot][48 + i] * wD[i];
    atomicAdd(&out[d * 32 + o], acc);
}

// ---------- fused readout tail: f1 -> f2 -> f3 -> f4 -> out, 4 graphs/block --
__global__ __launch_bounds__(256) void k_tail2(
    const float* __restrict__ f1,
    const float* __restrict__ mW2, const float* __restrict__ mb2,
    const float* __restrict__ mW3, const float* __restrict__ mb3,
    const float* __restrict__ mW4, const float* __restrict__ mb4,
    const float* __restrict__ mW5, const float* __restrict__ mb5,
    float* __restrict__ outv) {
    __shared__ float s1[4][256];
    __shared__ float s2[4][128];
    __shared__ float s3[4][32];
    __shared__ float s4[4][8];
    const int t  = threadIdx.x;
    const int g0 = blockIdx.x * 4;
#pragma unroll
    for (int i = 0; i < 4; ++i) {
        int idx = t + i * 256;
        s1[idx >> 8][idx & 255] = f1[g0 * 256 + idx];
    }
    __syncthreads();
#pragma unroll
    for (int i = 0; i < 2; ++i) {
        int idx = t + i * 256;
        int g = idx >> 7, cc = idx & 127;
        float acc = mb2[cc];
#pragma unroll 8
        for (int k = 0; k < 256; ++k) acc += s1[g][k] * mW2[k * 128 + cc];
        s2[g][cc] = fmaxf(acc, 0.f);
    }
    __syncthreads();
    const int w = t >> 6, lane = t & 63;
    if (lane < 32) {
        float acc = mb3[lane];
#pragma unroll 8
        for (int k = 0; k < 128; ++k) acc += s2[w][k] * mW3[k * 32 + lane];
        s3[w][lane] = fmaxf(acc, 0.f);
    }
    __syncthreads();
    if (lane < 8) {
        float acc = mb4[lane];
#pragma unroll
        for (int k = 0; k < 32; ++k) acc += s3[w][k] * mW4[k * 8 + lane];
        s4[w][lane] = fmaxf(acc, 0.f);
    }
    __syncthreads();
    if (lane == 0) {
        float acc = mb5[0];
#pragma unroll
        for (int k = 0; k < 8; ++k) acc += s4[w][k] * mW5[k];
        outv[g0 + w] = acc;
    }
}

extern "C" void kernel_launch(void* const* d_in, const int* in_sizes, int n_in,
                              void* d_out, int out_size, void* d_ws, size_t ws_size,
                              hipStream_t stream) {
    const int*   nf      = (const int*)d_in[0];
    const int*   ef      = (const int*)d_in[1];
    const int*   eidx    = (const int*)d_in[2];
    const float* atom_emb= (const float*)d_in[4];
    const float* bond_emb= (const float*)d_in[5];
    const float* gW1     = (const float*)d_in[6];
    const float* gW2     = (const float*)d_in[7];
    const float* gW3     = (const float*)d_in[8];
    const float* root    = (const float*)d_in[9];
    const float* cbias   = (const float*)d_in[10];
    const float* mW1     = (const float*)d_in[11];
    const float* mb1     = (const float*)d_in[12];
    const float* mW2     = (const float*)d_in[13];
    const float* mb2     = (const float*)d_in[14];
    const float* mW3     = (const float*)d_in[15];
    const float* mb3     = (const float*)d_in[16];
    const float* mW4     = (const float*)d_in[17];
    const float* mb4     = (const float*)d_in[18];
    const float* mW5     = (const float*)d_in[19];
    const float* mb5     = (const float*)d_in[20];

    const int* src = eidx;
    const int* dst = eidx + NEDGES;

    float* ws = (float*)d_ws;
    float* x    = ws;                        // 40960*64   = 2621440
    float* out  = x + 2621440;               // 40960*32   = 1310720
    float* h1   = out + 1310720;             // 512*1024   = 524288
    float* h2   = h1 + 524288;               // 512*256    = 131072
    float* wtab = h2 + 131072;               // 512*2048   = 1048576
    float* f1   = wtab + 1048576;            // 1024*256   = 262144
    float* part = f1 + 262144;               // 2097152 (8 MB split-K partials)

    // 1. fused atom encoder + root transform
    k_node<<<NNODES / 4, 256, 0, stream>>>(nf, atom_emb, root, cbias, x, out);
    // 2. h1 = relu(etab @ gW1), etab computed in-LDS per block
    k_h1<<<NCOMBO * 4, 256, 0, stream>>>(bond_emb, gW1, h1);
    // 3. h2 = relu(h1 @ gW2): 512x256, K=1024, split 16x64
    k_gemm_tiled<64, 64, 16, 4, 4><<<dim3(4, 8, 16), 256, 0, stream>>>(
        h1, gW2, nullptr, nullptr, part, NCOMBO, 256, 1024, 64, 0);
    k_reduceK<<<131072 / 1024, 256, 0, stream>>>(part, nullptr, h2, 131072, 256, 16, 1);
    // 4. wtab = h2 @ gW3: 512x2048, K=256, split 2x128
    k_gemm_tiled<64, 64, 16, 4, 4><<<dim3(32, 8, 2), 256, 0, stream>>>(
        h2, gW3, nullptr, nullptr, part, NCOMBO, 2048, 256, 128, 0);
    k_reduceK<<<1048576 / 1024, 256, 0, stream>>>(part, nullptr, wtab, 1048576, 2048, 2, 0);
    // 5. per-edge message + scatter: asm-pipelined W loads (counted vmcnt)
    k_msga<<<NEDGES / 8, 256, 0, stream>>>(x, wtab, ef, src, dst, out);
    // 6. f1 = relu(dense @ mW1 + mb1): 1024x256, K=1280, split 8x160
    k_gemm_tiled<64, 64, 16, 4, 4><<<dim3(4, 16, 8), 256, 0, stream>>>(
        out, mW1, nullptr, nullptr, part, NG, 256, 1280, 160, 0);
    k_reduceK<<<262144 / 1024, 256, 0, stream>>>(part, mb1, f1, 262144, 256, 8, 1);
    // 7. fused tail: f2, f3, f4, final
    k_tail2<<<NG / 4, 256, 0, stream>>>(f1, mW2, mb2, mW3, mb3, mW4, mb4,
                                        mW5, mb5, (float*)d_out);
}